// Round 4
// baseline (397.905 us; speedup 1.0000x reference)
//
#include <hip/hip_runtime.h>

// RGCNBlock: y = rgcn2(gelu(bn2(rgcn1(gelu(bn1(x)))))) + x
// N=50000 nodes, K=16 neighbors, F=128 features, f32 in/out.
// Matmuls in bf16 MFMA (16x16x32), stats/accum in f32. b1 cancels in BN2.
// rgcn: 1-wave blocks (32 nodes), K=16 per wave, indices preloaded,
// 1-deep double-buffered A-gather, fully unrolled k-loop (static regs).
// R3 lesson: do NOT cap VGPRs (launch_bounds min-waves) below working set.

#define NN 50000
#define FF 128

typedef __bf16 v8bf __attribute__((ext_vector_type(8)));
typedef float  v4f  __attribute__((ext_vector_type(4)));

__device__ __forceinline__ unsigned short f2bf(float f) {
  unsigned int u = __builtin_bit_cast(unsigned int, f);
  u += 0x7FFFu + ((u >> 16) & 1u);          // RNE
  return (unsigned short)(u >> 16);
}
__device__ __forceinline__ float bf2f(unsigned short s) {
  unsigned int u = ((unsigned int)s) << 16;
  return __builtin_bit_cast(float, u);
}
__device__ __forceinline__ float gelu_f(float y) {
  return 0.5f * y * (1.0f + erff(y * 0.70710678118654752f));
}

// ---------------- W (F x K*F f32) -> bf16 in MFMA-B-fragment order ----------
// frag id = k4*8 + c  (k4 = 32-wide K-window 0..63, c = 16-wide col tile 0..7)
// within frag: lane L holds W[c*16+(L&15), k4*32+(L>>4)*8 + j], j=0..7 (16B)
__global__ void wconv_kernel(const float* __restrict__ W1, const float* __restrict__ W2,
                             unsigned short* __restrict__ Wt1, unsigned short* __restrict__ Wt2) {
  int t = blockIdx.x * 256 + threadIdx.x;            // 65536 total
  const float* W = (t >= 32768) ? W2 : W1;
  unsigned short* Wt = (t >= 32768) ? Wt2 : Wt1;
  int r = t & 32767;
  int frag = r >> 6, lane = r & 63;
  int k4 = frag >> 3, c = frag & 7;
  int o  = c * 16 + (lane & 15);
  int kd = k4 * 32 + (lane >> 4) * 8;
  const float* src = W + o * 2048 + kd;
  unsigned short* dst = Wt + r * 8;
#pragma unroll
  for (int j = 0; j < 8; ++j) dst[j] = f2bf(src[j]);
}

// ---------------- BN stats over x (f32), deterministic two-phase ------------
__global__ void bn_stats_kernel(const float* __restrict__ x, float* __restrict__ part) {
  float s0=0,s1=0,s2=0,s3=0,q0=0,q1=0,q2=0,q3=0;
  for (int cb = blockIdx.x; cb < (NN*FF/1024); cb += 256) {
    float4 v = reinterpret_cast<const float4*>(x)[cb * 256 + threadIdx.x];
    s0+=v.x; q0+=v.x*v.x; s1+=v.y; q1+=v.y*v.y;
    s2+=v.z; q2+=v.z*v.z; s3+=v.w; q3+=v.w*v.w;
  }
  __shared__ float ls[1024], lsq[1024];
  int fb = (threadIdx.x & 31) * 4;
  int sl = threadIdx.x >> 5;
  ls[sl*128+fb]   = s0; ls[sl*128+fb+1]  = s1; ls[sl*128+fb+2]  = s2; ls[sl*128+fb+3]  = s3;
  lsq[sl*128+fb]  = q0; lsq[sl*128+fb+1] = q1; lsq[sl*128+fb+2] = q2; lsq[sl*128+fb+3] = q3;
  __syncthreads();
  if (threadIdx.x < 128) {
    float S=0,Q=0;
#pragma unroll
    for (int s2i=0; s2i<8; ++s2i){ S += ls[s2i*128+threadIdx.x]; Q += lsq[s2i*128+threadIdx.x]; }
    part[blockIdx.x*256 + threadIdx.x]       = S;
    part[blockIdx.x*256 + 128 + threadIdx.x] = Q;
  }
}

// ---------------- final reduce: 1 block x 1024 thr, 8 groups x 128 feats ----
__global__ __launch_bounds__(1024) void bn_reduce_kernel(
    const float* __restrict__ part, int nb,
    const float* __restrict__ gamma, const float* __restrict__ beta,
    float* __restrict__ scsh) {
  int f = threadIdx.x & 127;
  int g = threadIdx.x >> 7;                            // 0..7
  float S = 0.f, Q = 0.f;
  for (int b = g; b < nb; b += 8) {                    // independent loads, deep pipeline
    S += part[b * 256 + f];
    Q += part[b * 256 + 128 + f];
  }
  __shared__ float ls[8][128], lq[8][128];
  ls[g][f] = S; lq[g][f] = Q;
  __syncthreads();
  if (threadIdx.x < 128) {
    float St = 0.f, Qt = 0.f;
#pragma unroll
    for (int i = 0; i < 8; ++i) { St += ls[i][f]; Qt += lq[i][f]; }
    float inv  = 1.0f / (float)NN;
    float mean = St * inv;
    float var  = fmaxf(Qt * inv - mean * mean, 0.0f);
    float sc   = gamma[f] * rsqrtf(var + 1e-5f);
    scsh[f]       = sc;
    scsh[128 + f] = beta[f] - mean * sc;
  }
}

// ---------------- apply BN + GELU, f32 source -> bf16 ----------------------
__global__ void apply1_kernel(const float* __restrict__ x, const float* __restrict__ scsh,
                              unsigned short* __restrict__ h1) {
  int stride = gridDim.x * blockDim.x;
  for (int c = blockIdx.x * blockDim.x + threadIdx.x; c < NN*FF/4; c += stride) {
    float4 v = reinterpret_cast<const float4*>(x)[c];
    int f = (c * 4) & 127;
    ushort4 o;
    o.x = f2bf(gelu_f(v.x * scsh[f]   + scsh[128+f]));
    o.y = f2bf(gelu_f(v.y * scsh[f+1] + scsh[128+f+1]));
    o.z = f2bf(gelu_f(v.z * scsh[f+2] + scsh[128+f+2]));
    o.w = f2bf(gelu_f(v.w * scsh[f+3] + scsh[128+f+3]));
    reinterpret_cast<ushort4*>(h1)[c] = o;
  }
}

// ---------------- apply BN + GELU, bf16 source -> bf16 ---------------------
__global__ void apply2_kernel(const unsigned short* __restrict__ t1, const float* __restrict__ scsh,
                              unsigned short* __restrict__ h2) {
  int stride = gridDim.x * blockDim.x;
  for (int c = blockIdx.x * blockDim.x + threadIdx.x; c < NN*FF/4; c += stride) {
    ushort4 v = reinterpret_cast<const ushort4*>(t1)[c];
    int f = (c * 4) & 127;
    ushort4 o;
    o.x = f2bf(gelu_f(bf2f(v.x) * scsh[f]   + scsh[128+f]));
    o.y = f2bf(gelu_f(bf2f(v.y) * scsh[f+1] + scsh[128+f+1]));
    o.z = f2bf(gelu_f(bf2f(v.z) * scsh[f+2] + scsh[128+f+2]));
    o.w = f2bf(gelu_f(bf2f(v.w) * scsh[f+3] + scsh[128+f+3]));
    reinterpret_cast<ushort4*>(h2)[c] = o;
  }
}

// ---------------- RGCN: out[n,o] = sum_{k,f} h[nbr[n,k],f] * W[o,k*128+f] --
// Block = 1 wave = 32 nodes (rf=0: rows 0..15, rf=1: rows 16..31), K=16.
// All 16 neighbor indices preloaded (int4); A gathered global->VGPR with
// 1-deep double buffer; B coalesced from swizzled Wt (L2-resident).
template<bool STATS>
__global__ __launch_bounds__(64) void rgcn_kernel(
    const unsigned short* __restrict__ h,
    const unsigned short* __restrict__ Wt,
    const int* __restrict__ graph,
    const float* __restrict__ bias,
    const float* __restrict__ xres,
    float* __restrict__ outf,
    unsigned short* __restrict__ outb,
    float* __restrict__ part)
{
  const int lane = threadIdx.x & 63;
  const int l15  = lane & 15;
  const int lq   = lane >> 4;
  const int nodebase = blockIdx.x * 32;

  v4f acc[2][8];
#pragma unroll
  for (int rf = 0; rf < 2; ++rf)
#pragma unroll
    for (int c = 0; c < 8; ++c) acc[rf][c] = (v4f){0.f, 0.f, 0.f, 0.f};

  const int an0 = min(nodebase + l15, NN - 1);       // A-row node (rf=0)
  const int an1 = min(nodebase + 16 + l15, NN - 1);  // A-row node (rf=1)

  // preload all 16 neighbor indices per row (odd ints of graph pairs)
  int idx0[16], idx1[16];
  {
    const int4* g0 = reinterpret_cast<const int4*>(graph + an0 * 32);
    const int4* g1 = reinterpret_cast<const int4*>(graph + an1 * 32);
#pragma unroll
    for (int j = 0; j < 8; ++j) {
      int4 t0 = g0[j], t1v = g1[j];
      idx0[2*j]   = min(max(t0.y, 0), NN - 1);
      idx0[2*j+1] = min(max(t0.w, 0), NN - 1);
      idx1[2*j]   = min(max(t1v.y, 0), NN - 1);
      idx1[2*j+1] = min(max(t1v.w, 0), NN - 1);
    }
  }

  v8bf A0[2][4], A1[2][4];
#define LOADA(buf, s_) {                                              \
    const unsigned short* r0 = h + idx0[s_] * 128 + lq * 8;           \
    const unsigned short* r1 = h + idx1[s_] * 128 + lq * 8;           \
    _Pragma("unroll")                                                 \
    for (int w4 = 0; w4 < 4; ++w4) {                                  \
      A0[buf][w4] = *reinterpret_cast<const v8bf*>(r0 + w4 * 32);     \
      A1[buf][w4] = *reinterpret_cast<const v8bf*>(r1 + w4 * 32);     \
    }                                                                 \
  }

  LOADA(0, 0);                                       // prologue: slot 0
  const unsigned short* wlane = Wt + lane * 8;

#pragma unroll
  for (int s = 0; s < 16; ++s) {                     // fully unrolled: static regs
    const int cur = s & 1;
    if (s < 15) LOADA(cur ^ 1, s + 1);               // prefetch next slot
    const unsigned short* wp = wlane + s * 16384;
#pragma unroll
    for (int w4 = 0; w4 < 4; ++w4) {
#pragma unroll
      for (int c = 0; c < 8; ++c) {
        v8bf b = *reinterpret_cast<const v8bf*>(wp + w4 * 4096 + c * 512);
        acc[0][c] = __builtin_amdgcn_mfma_f32_16x16x32_bf16(A0[cur][w4], b, acc[0][c], 0, 0, 0);
        acc[1][c] = __builtin_amdgcn_mfma_f32_16x16x32_bf16(A1[cur][w4], b, acc[1][c], 0, 0, 0);
      }
    }
  }
#undef LOADA

  if constexpr (STATS) {
    // per-wave column sums -> part[block], no LDS, no barrier
#pragma unroll
    for (int c = 0; c < 8; ++c) {
      float s = 0.f, q = 0.f;
#pragma unroll
      for (int rf = 0; rf < 2; ++rf) {
#pragma unroll
        for (int j = 0; j < 4; ++j) {
          int node = nodebase + rf * 16 + lq * 4 + j;   // C/D: row=(lane>>4)*4+reg
          float v  = acc[rf][c][j];
          if (node < NN) {
            s += v; q += v * v;
            outb[node * 128 + c * 16 + l15] = f2bf(v);  // col = lane&15
          }
        }
      }
      s += __shfl_xor(s, 16, 64); s += __shfl_xor(s, 32, 64);
      q += __shfl_xor(q, 16, 64); q += __shfl_xor(q, 32, 64);
      if (lq == 0) {
        part[blockIdx.x * 256 + c * 16 + l15]       = s;
        part[blockIdx.x * 256 + 128 + c * 16 + l15] = q;
      }
    }
  } else {
#pragma unroll
    for (int c = 0; c < 8; ++c) {
      float bv = bias[c * 16 + l15];
#pragma unroll
      for (int rf = 0; rf < 2; ++rf) {
#pragma unroll
        for (int j = 0; j < 4; ++j) {
          int node = nodebase + rf * 16 + lq * 4 + j;
          if (node < NN) {
            int idx = node * 128 + c * 16 + l15;
            outf[idx] = acc[rf][c][j] + bv + xres[idx];
          }
        }
      }
    }
  }
}

extern "C" void kernel_launch(void* const* d_in, const int* in_sizes, int n_in,
                              void* d_out, int out_size, void* d_ws, size_t ws_size,
                              hipStream_t stream) {
  const float* x      = (const float*)d_in[0];
  const int*   graph  = (const int*)d_in[1];
  const float* gamma1 = (const float*)d_in[2];
  const float* beta1  = (const float*)d_in[3];
  const float* W1     = (const float*)d_in[4];
  // d_in[5] = b1 : provably cancels inside BN2 (per-feature shift), skipped
  const float* gamma2 = (const float*)d_in[6];
  const float* beta2  = (const float*)d_in[7];
  const float* W2     = (const float*)d_in[8];
  const float* b2     = (const float*)d_in[9];
  float* out = (float*)d_out;

  char* ws = (char*)d_ws;
  // ws layout (bytes): h1/h2 bf16 12.8M | t1 bf16 12.8M | Wt1 512K | Wt2 512K
  //                    | p1 256K | scsh1 1K | scsh2 1K  (~27MB total)
  // p2 (1563 blocks x 1KB = 1.6MB) lives in d_out: written by rgcn1, read by
  // bn_reduce2, then fully overwritten by rgcn2 (stream-ordered, deterministic).
  unsigned short* h1  = (unsigned short*)(ws);
  unsigned short* t1  = (unsigned short*)(ws + 12800000);
  unsigned short* Wt1 = (unsigned short*)(ws + 25600000);
  unsigned short* Wt2 = (unsigned short*)(ws + 26124288);
  float* p1    = (float*)(ws + 26648576);
  float* scsh1 = (float*)(ws + 26910720);
  float* scsh2 = (float*)(ws + 26911744);
  float* p2    = out;

  wconv_kernel<<<256, 256, 0, stream>>>(W1, W2, Wt1, Wt2);
  bn_stats_kernel<<<256, 256, 0, stream>>>(x, p1);
  bn_reduce_kernel<<<1, 1024, 0, stream>>>(p1, 256, gamma1, beta1, scsh1);
  apply1_kernel<<<2048, 256, 0, stream>>>(x, scsh1, h1);
  rgcn_kernel<true><<<1563, 64, 0, stream>>>(h1, Wt1, graph, nullptr, nullptr, nullptr, t1, p2);
  bn_reduce_kernel<<<1, 1024, 0, stream>>>(p2, 1563, gamma2, beta2, scsh2);
  apply2_kernel<<<2048, 256, 0, stream>>>(t1, scsh2, h1);   // h2 reuses h1 buffer
  rgcn_kernel<false><<<1563, 64, 0, stream>>>(h1, Wt2, graph, b2, x, out, nullptr, nullptr);
}

// Round 5
// 340.422 us; speedup vs baseline: 1.1689x; 1.1689x over previous
//
#include <hip/hip_runtime.h>

// RGCNBlock: y = rgcn2(gelu(bn2(rgcn1(gelu(bn1(x)))))) + x
// N=50000 nodes, K=16 neighbors, F=128 features, f32 in/out.
// Matmuls in bf16 MFMA (16x16x32), stats/accum in f32. b1 cancels in BN2.
// rgcn: R2 shape (4-wave/128-node blocks, 391 blocks) + depth-3 A-prefetch
// with 4 rotating reg buffers, fully unrolled (all indices static), and
// __launch_bounds__(256,1) so the allocator KEEPS the pipeline (R3/R4 died
// from VGPR caps 76/84 collapsing the double buffer).

#define NN 50000
#define FF 128

typedef __bf16 v8bf __attribute__((ext_vector_type(8)));
typedef float  v4f  __attribute__((ext_vector_type(4)));

__device__ __forceinline__ unsigned short f2bf(float f) {
  unsigned int u = __builtin_bit_cast(unsigned int, f);
  u += 0x7FFFu + ((u >> 16) & 1u);          // RNE
  return (unsigned short)(u >> 16);
}
__device__ __forceinline__ float bf2f(unsigned short s) {
  unsigned int u = ((unsigned int)s) << 16;
  return __builtin_bit_cast(float, u);
}
__device__ __forceinline__ float gelu_f(float y) {
  return 0.5f * y * (1.0f + erff(y * 0.70710678118654752f));
}

// ---------------- W (F x K*F f32) -> bf16 in MFMA-B-fragment order ----------
// frag id = k4*8 + c  (k4 = 32-wide K-window 0..63, c = 16-wide col tile 0..7)
// within frag: lane L holds W[c*16+(L&15), k4*32+(L>>4)*8 + j], j=0..7 (16B)
__global__ void wconv_kernel(const float* __restrict__ W1, const float* __restrict__ W2,
                             unsigned short* __restrict__ Wt1, unsigned short* __restrict__ Wt2) {
  int t = blockIdx.x * 256 + threadIdx.x;            // 65536 total
  const float* W = (t >= 32768) ? W2 : W1;
  unsigned short* Wt = (t >= 32768) ? Wt2 : Wt1;
  int r = t & 32767;
  int frag = r >> 6, lane = r & 63;
  int k4 = frag >> 3, c = frag & 7;
  int o  = c * 16 + (lane & 15);
  int kd = k4 * 32 + (lane >> 4) * 8;
  const float* src = W + o * 2048 + kd;
  unsigned short* dst = Wt + r * 8;
#pragma unroll
  for (int j = 0; j < 8; ++j) dst[j] = f2bf(src[j]);
}

// ---------------- BN stats over x (f32), deterministic two-phase ------------
__global__ void bn_stats_kernel(const float* __restrict__ x, float* __restrict__ part) {
  float s0=0,s1=0,s2=0,s3=0,q0=0,q1=0,q2=0,q3=0;
  for (int cb = blockIdx.x; cb < (NN*FF/1024); cb += 256) {
    float4 v = reinterpret_cast<const float4*>(x)[cb * 256 + threadIdx.x];
    s0+=v.x; q0+=v.x*v.x; s1+=v.y; q1+=v.y*v.y;
    s2+=v.z; q2+=v.z*v.z; s3+=v.w; q3+=v.w*v.w;
  }
  __shared__ float ls[1024], lsq[1024];
  int fb = (threadIdx.x & 31) * 4;
  int sl = threadIdx.x >> 5;
  ls[sl*128+fb]   = s0; ls[sl*128+fb+1]  = s1; ls[sl*128+fb+2]  = s2; ls[sl*128+fb+3]  = s3;
  lsq[sl*128+fb]  = q0; lsq[sl*128+fb+1] = q1; lsq[sl*128+fb+2] = q2; lsq[sl*128+fb+3] = q3;
  __syncthreads();
  if (threadIdx.x < 128) {
    float S=0,Q=0;
#pragma unroll
    for (int s2i=0; s2i<8; ++s2i){ S += ls[s2i*128+threadIdx.x]; Q += lsq[s2i*128+threadIdx.x]; }
    part[blockIdx.x*256 + threadIdx.x]       = S;
    part[blockIdx.x*256 + 128 + threadIdx.x] = Q;
  }
}

// ---------------- final reduce: 1 block x 1024 thr, 8 groups x 128 feats ----
__global__ __launch_bounds__(1024) void bn_reduce_kernel(
    const float* __restrict__ part, int nb,
    const float* __restrict__ gamma, const float* __restrict__ beta,
    float* __restrict__ scsh) {
  int f = threadIdx.x & 127;
  int g = threadIdx.x >> 7;                            // 0..7
  float S = 0.f, Q = 0.f;
  for (int b = g; b < nb; b += 8) {                    // independent loads, deep pipeline
    S += part[b * 256 + f];
    Q += part[b * 256 + 128 + f];
  }
  __shared__ float ls[8][128], lq[8][128];
  ls[g][f] = S; lq[g][f] = Q;
  __syncthreads();
  if (threadIdx.x < 128) {
    float St = 0.f, Qt = 0.f;
#pragma unroll
    for (int i = 0; i < 8; ++i) { St += ls[i][f]; Qt += lq[i][f]; }
    float inv  = 1.0f / (float)NN;
    float mean = St * inv;
    float var  = fmaxf(Qt * inv - mean * mean, 0.0f);
    float sc   = gamma[f] * rsqrtf(var + 1e-5f);
    scsh[f]       = sc;
    scsh[128 + f] = beta[f] - mean * sc;
  }
}

// ---------------- apply BN + GELU, f32 source -> bf16 ----------------------
__global__ void apply1_kernel(const float* __restrict__ x, const float* __restrict__ scsh,
                              unsigned short* __restrict__ h1) {
  int stride = gridDim.x * blockDim.x;
  for (int c = blockIdx.x * blockDim.x + threadIdx.x; c < NN*FF/4; c += stride) {
    float4 v = reinterpret_cast<const float4*>(x)[c];
    int f = (c * 4) & 127;
    ushort4 o;
    o.x = f2bf(gelu_f(v.x * scsh[f]   + scsh[128+f]));
    o.y = f2bf(gelu_f(v.y * scsh[f+1] + scsh[128+f+1]));
    o.z = f2bf(gelu_f(v.z * scsh[f+2] + scsh[128+f+2]));
    o.w = f2bf(gelu_f(v.w * scsh[f+3] + scsh[128+f+3]));
    reinterpret_cast<ushort4*>(h1)[c] = o;
  }
}

// ---------------- apply BN + GELU, bf16 source -> bf16 ---------------------
__global__ void apply2_kernel(const unsigned short* __restrict__ t1, const float* __restrict__ scsh,
                              unsigned short* __restrict__ h2) {
  int stride = gridDim.x * blockDim.x;
  for (int c = blockIdx.x * blockDim.x + threadIdx.x; c < NN*FF/4; c += stride) {
    ushort4 v = reinterpret_cast<const ushort4*>(t1)[c];
    int f = (c * 4) & 127;
    ushort4 o;
    o.x = f2bf(gelu_f(bf2f(v.x) * scsh[f]   + scsh[128+f]));
    o.y = f2bf(gelu_f(bf2f(v.y) * scsh[f+1] + scsh[128+f+1]));
    o.z = f2bf(gelu_f(bf2f(v.z) * scsh[f+2] + scsh[128+f+2]));
    o.w = f2bf(gelu_f(bf2f(v.w) * scsh[f+3] + scsh[128+f+3]));
    reinterpret_cast<ushort4*>(h2)[c] = o;
  }
}

// ---------------- RGCN: out[n,o] = sum_{k,f} h[nbr[n,k],f] * W[o,k*128+f] --
// Block = 4 waves, 128 nodes. Wave = 32 nodes x 128 out-feats, all 16 slots.
// Indices preloaded (int4, pre-scaled). A gathered global->VGPR, depth-3
// prefetch over 4 rotating buffers, fully unrolled. B streamed from Wt.
// Per-slot issue order: [B(t) x32 + MFMA(t)] then [gather(t+3) x8], so MFMA
// vmcnt waits never drain the in-flight prefetch (in-order vmcnt).
template<bool STATS>
__global__ __launch_bounds__(256, 1) void rgcn_kernel(
    const unsigned short* __restrict__ h,
    const unsigned short* __restrict__ Wt,
    const int* __restrict__ graph,
    const float* __restrict__ bias,
    const float* __restrict__ xres,
    float* __restrict__ outf,
    unsigned short* __restrict__ outb,
    float* __restrict__ part)
{
  const int tid  = threadIdx.x;
  const int wv   = tid >> 6;
  const int lane = tid & 63;
  const int l15  = lane & 15;
  const int lq   = lane >> 4;
  const int nodebase = blockIdx.x * 128 + wv * 32;

  v4f acc[2][8];
#pragma unroll
  for (int rf = 0; rf < 2; ++rf)
#pragma unroll
    for (int c = 0; c < 8; ++c) acc[rf][c] = (v4f){0.f, 0.f, 0.f, 0.f};

  const int an0 = min(nodebase + l15, NN - 1);       // A-row node (rf=0)
  const int an1 = min(nodebase + 16 + l15, NN - 1);  // A-row node (rf=1)

  // preload all 16 neighbor indices per row, clamped, pre-scaled to row offset
  int idx0[16], idx1[16];
  {
    const int4* g0 = reinterpret_cast<const int4*>(graph + an0 * 32);
    const int4* g1 = reinterpret_cast<const int4*>(graph + an1 * 32);
#pragma unroll
    for (int j = 0; j < 8; ++j) {
      int4 t0 = g0[j], t1v = g1[j];
      idx0[2*j]   = min(max(t0.y,  0), NN - 1) * 128;
      idx0[2*j+1] = min(max(t0.w,  0), NN - 1) * 128;
      idx1[2*j]   = min(max(t1v.y, 0), NN - 1) * 128;
      idx1[2*j+1] = min(max(t1v.w, 0), NN - 1) * 128;
    }
  }

  v8bf A0[4][4], A1[4][4];                           // 4 rotating slot buffers
#define GATHER(s_) {                                                  \
    const unsigned short* r0 = h + idx0[s_] + lq * 8;                 \
    const unsigned short* r1 = h + idx1[s_] + lq * 8;                 \
    _Pragma("unroll")                                                 \
    for (int w4 = 0; w4 < 4; ++w4) {                                  \
      A0[(s_) & 3][w4] = *reinterpret_cast<const v8bf*>(r0 + w4*32);  \
      A1[(s_) & 3][w4] = *reinterpret_cast<const v8bf*>(r1 + w4*32);  \
    }                                                                 \
  }

  const unsigned short* wlane = Wt + lane * 8;

  GATHER(0) GATHER(1) GATHER(2)                      // prologue: 3 slots in flight

#define BODY(t_) {                                                         \
    const unsigned short* wp = wlane + (t_) * 16384;                       \
    _Pragma("unroll")                                                      \
    for (int w4 = 0; w4 < 4; ++w4) {                                       \
      _Pragma("unroll")                                                    \
      for (int c = 0; c < 8; ++c) {                                        \
        v8bf b = *reinterpret_cast<const v8bf*>(wp + w4*4096 + c*512);     \
        acc[0][c] = __builtin_amdgcn_mfma_f32_16x16x32_bf16(               \
                      A0[(t_) & 3][w4], b, acc[0][c], 0, 0, 0);            \
        acc[1][c] = __builtin_amdgcn_mfma_f32_16x16x32_bf16(               \
                      A1[(t_) & 3][w4], b, acc[1][c], 0, 0, 0);            \
      }                                                                    \
    }                                                                      \
    if ((t_) + 3 < 16) GATHER((t_) + 3)                                    \
  }

  BODY(0)  BODY(1)  BODY(2)  BODY(3)
  BODY(4)  BODY(5)  BODY(6)  BODY(7)
  BODY(8)  BODY(9)  BODY(10) BODY(11)
  BODY(12) BODY(13) BODY(14) BODY(15)
#undef BODY
#undef GATHER

  if constexpr (STATS) {
    __shared__ float lds_s[4][128];
    __shared__ float lds_q[4][128];
#pragma unroll
    for (int c = 0; c < 8; ++c) {
      float s = 0.f, q = 0.f;
#pragma unroll
      for (int rf = 0; rf < 2; ++rf) {
#pragma unroll
        for (int j = 0; j < 4; ++j) {
          int node = nodebase + rf * 16 + lq * 4 + j;   // C/D: row=(lane>>4)*4+reg
          float v  = acc[rf][c][j];
          if (node < NN) {
            s += v; q += v * v;
            outb[node * 128 + c * 16 + l15] = f2bf(v);  // col = lane&15
          }
        }
      }
      s += __shfl_xor(s, 16, 64); s += __shfl_xor(s, 32, 64);
      q += __shfl_xor(q, 16, 64); q += __shfl_xor(q, 32, 64);
      if (lq == 0) { lds_s[wv][c * 16 + l15] = s; lds_q[wv][c * 16 + l15] = q; }
    }
    __syncthreads();
    if (tid < 128) {
      float S = lds_s[0][tid] + lds_s[1][tid] + lds_s[2][tid] + lds_s[3][tid];
      float Q = lds_q[0][tid] + lds_q[1][tid] + lds_q[2][tid] + lds_q[3][tid];
      part[blockIdx.x * 256 + tid]       = S;
      part[blockIdx.x * 256 + 128 + tid] = Q;
    }
  } else {
#pragma unroll
    for (int c = 0; c < 8; ++c) {
      float bv = bias[c * 16 + l15];
#pragma unroll
      for (int rf = 0; rf < 2; ++rf) {
#pragma unroll
        for (int j = 0; j < 4; ++j) {
          int node = nodebase + rf * 16 + lq * 4 + j;
          if (node < NN) {
            int idx = node * 128 + c * 16 + l15;
            outf[idx] = acc[rf][c][j] + bv + xres[idx];
          }
        }
      }
    }
  }
}

extern "C" void kernel_launch(void* const* d_in, const int* in_sizes, int n_in,
                              void* d_out, int out_size, void* d_ws, size_t ws_size,
                              hipStream_t stream) {
  const float* x      = (const float*)d_in[0];
  const int*   graph  = (const int*)d_in[1];
  const float* gamma1 = (const float*)d_in[2];
  const float* beta1  = (const float*)d_in[3];
  const float* W1     = (const float*)d_in[4];
  // d_in[5] = b1 : provably cancels inside BN2 (per-feature shift), skipped
  const float* gamma2 = (const float*)d_in[6];
  const float* beta2  = (const float*)d_in[7];
  const float* W2     = (const float*)d_in[8];
  const float* b2     = (const float*)d_in[9];
  float* out = (float*)d_out;

  char* ws = (char*)d_ws;
  // ws layout (bytes): h1/h2 bf16 12.8M | t1 bf16 12.8M | Wt1 512K | Wt2 512K
  //                    | p1 256K | p2 400K | scsh1 1K | scsh2 1K   (~27.3MB total)
  unsigned short* h1  = (unsigned short*)(ws);
  unsigned short* t1  = (unsigned short*)(ws + 12800000);
  unsigned short* Wt1 = (unsigned short*)(ws + 25600000);
  unsigned short* Wt2 = (unsigned short*)(ws + 26124288);
  float* p1    = (float*)(ws + 26648576);
  float* p2    = (float*)(ws + 26910720);
  float* scsh1 = (float*)(ws + 27311104);
  float* scsh2 = (float*)(ws + 27312128);

  wconv_kernel<<<256, 256, 0, stream>>>(W1, W2, Wt1, Wt2);
  bn_stats_kernel<<<256, 256, 0, stream>>>(x, p1);
  bn_reduce_kernel<<<1, 1024, 0, stream>>>(p1, 256, gamma1, beta1, scsh1);
  apply1_kernel<<<2048, 256, 0, stream>>>(x, scsh1, h1);
  rgcn_kernel<true><<<391, 256, 0, stream>>>(h1, Wt1, graph, nullptr, nullptr, nullptr, t1, p2);
  bn_reduce_kernel<<<1, 1024, 0, stream>>>(p2, 391, gamma2, beta2, scsh2);
  apply2_kernel<<<2048, 256, 0, stream>>>(t1, scsh2, h1);   // h2 reuses h1 buffer
  rgcn_kernel<false><<<391, 256, 0, stream>>>(h1, Wt2, graph, b2, x, out, nullptr, nullptr);
}

// Round 6
// 207.734 us; speedup vs baseline: 1.9155x; 1.6387x over previous
//
#include <hip/hip_runtime.h>

// RGCNBlock: y = rgcn2(gelu(bn2(rgcn1(gelu(bn1(x)))))) + x
// N=50000 nodes, K=16 neighbors, F=128 features, f32 in/out.
// Matmuls in bf16 MFMA (16x16x32), stats/accum in f32. b1 cancels in BN2.
// rgcn R6: B staged to LDS via global_load_lds (async, no VGPR to sink),
// double-buffered, one __syncthreads per slot = structural fence the
// scheduler cannot sink loads across (R3/R4/R5 all died from gather-sink).
// A gathered to VGPRs 1-deep, pinned by sched_barrier(0) before MFMAs.

#define NN 50000
#define FF 128

typedef __bf16 v8bf __attribute__((ext_vector_type(8)));
typedef float  v4f  __attribute__((ext_vector_type(4)));

__device__ __forceinline__ unsigned short f2bf(float f) {
  unsigned int u = __builtin_bit_cast(unsigned int, f);
  u += 0x7FFFu + ((u >> 16) & 1u);          // RNE
  return (unsigned short)(u >> 16);
}
__device__ __forceinline__ float bf2f(unsigned short s) {
  unsigned int u = ((unsigned int)s) << 16;
  return __builtin_bit_cast(float, u);
}
__device__ __forceinline__ float gelu_f(float y) {
  return 0.5f * y * (1.0f + erff(y * 0.70710678118654752f));
}

// ---------------- W (F x K*F f32) -> bf16 in MFMA-B-fragment order ----------
// frag id = k4*8 + c  (k4 = 32-wide K-window 0..63, c = 16-wide col tile 0..7)
// within frag: lane L holds W[c*16+(L&15), k4*32+(L>>4)*8 + j], j=0..7 (16B)
__global__ void wconv_kernel(const float* __restrict__ W1, const float* __restrict__ W2,
                             unsigned short* __restrict__ Wt1, unsigned short* __restrict__ Wt2) {
  int t = blockIdx.x * 256 + threadIdx.x;            // 65536 total
  const float* W = (t >= 32768) ? W2 : W1;
  unsigned short* Wt = (t >= 32768) ? Wt2 : Wt1;
  int r = t & 32767;
  int frag = r >> 6, lane = r & 63;
  int k4 = frag >> 3, c = frag & 7;
  int o  = c * 16 + (lane & 15);
  int kd = k4 * 32 + (lane >> 4) * 8;
  const float* src = W + o * 2048 + kd;
  unsigned short* dst = Wt + r * 8;
#pragma unroll
  for (int j = 0; j < 8; ++j) dst[j] = f2bf(src[j]);
}

// ---------------- BN stats over x (f32), deterministic two-phase ------------
__global__ void bn_stats_kernel(const float* __restrict__ x, float* __restrict__ part) {
  float s0=0,s1=0,s2=0,s3=0,q0=0,q1=0,q2=0,q3=0;
  for (int cb = blockIdx.x; cb < (NN*FF/1024); cb += 256) {
    float4 v = reinterpret_cast<const float4*>(x)[cb * 256 + threadIdx.x];
    s0+=v.x; q0+=v.x*v.x; s1+=v.y; q1+=v.y*v.y;
    s2+=v.z; q2+=v.z*v.z; s3+=v.w; q3+=v.w*v.w;
  }
  __shared__ float ls[1024], lsq[1024];
  int fb = (threadIdx.x & 31) * 4;
  int sl = threadIdx.x >> 5;
  ls[sl*128+fb]   = s0; ls[sl*128+fb+1]  = s1; ls[sl*128+fb+2]  = s2; ls[sl*128+fb+3]  = s3;
  lsq[sl*128+fb]  = q0; lsq[sl*128+fb+1] = q1; lsq[sl*128+fb+2] = q2; lsq[sl*128+fb+3] = q3;
  __syncthreads();
  if (threadIdx.x < 128) {
    float S=0,Q=0;
#pragma unroll
    for (int s2i=0; s2i<8; ++s2i){ S += ls[s2i*128+threadIdx.x]; Q += lsq[s2i*128+threadIdx.x]; }
    part[blockIdx.x*256 + threadIdx.x]       = S;
    part[blockIdx.x*256 + 128 + threadIdx.x] = Q;
  }
}

// ---------------- final reduce: 1 block x 1024 thr, 8 groups x 128 feats ----
__global__ __launch_bounds__(1024) void bn_reduce_kernel(
    const float* __restrict__ part, int nb,
    const float* __restrict__ gamma, const float* __restrict__ beta,
    float* __restrict__ scsh) {
  int f = threadIdx.x & 127;
  int g = threadIdx.x >> 7;                            // 0..7
  float S = 0.f, Q = 0.f;
  for (int b = g; b < nb; b += 8) {                    // independent loads, deep pipeline
    S += part[b * 256 + f];
    Q += part[b * 256 + 128 + f];
  }
  __shared__ float ls[8][128], lq[8][128];
  ls[g][f] = S; lq[g][f] = Q;
  __syncthreads();
  if (threadIdx.x < 128) {
    float St = 0.f, Qt = 0.f;
#pragma unroll
    for (int i = 0; i < 8; ++i) { St += ls[i][f]; Qt += lq[i][f]; }
    float inv  = 1.0f / (float)NN;
    float mean = St * inv;
    float var  = fmaxf(Qt * inv - mean * mean, 0.0f);
    float sc   = gamma[f] * rsqrtf(var + 1e-5f);
    scsh[f]       = sc;
    scsh[128 + f] = beta[f] - mean * sc;
  }
}

// ---------------- apply BN + GELU, f32 source -> bf16 ----------------------
__global__ void apply1_kernel(const float* __restrict__ x, const float* __restrict__ scsh,
                              unsigned short* __restrict__ h1) {
  int stride = gridDim.x * blockDim.x;
  for (int c = blockIdx.x * blockDim.x + threadIdx.x; c < NN*FF/4; c += stride) {
    float4 v = reinterpret_cast<const float4*>(x)[c];
    int f = (c * 4) & 127;
    ushort4 o;
    o.x = f2bf(gelu_f(v.x * scsh[f]   + scsh[128+f]));
    o.y = f2bf(gelu_f(v.y * scsh[f+1] + scsh[128+f+1]));
    o.z = f2bf(gelu_f(v.z * scsh[f+2] + scsh[128+f+2]));
    o.w = f2bf(gelu_f(v.w * scsh[f+3] + scsh[128+f+3]));
    reinterpret_cast<ushort4*>(h1)[c] = o;
  }
}

// ---------------- apply BN + GELU, bf16 source -> bf16 ---------------------
__global__ void apply2_kernel(const unsigned short* __restrict__ t1, const float* __restrict__ scsh,
                              unsigned short* __restrict__ h2) {
  int stride = gridDim.x * blockDim.x;
  for (int c = blockIdx.x * blockDim.x + threadIdx.x; c < NN*FF/4; c += stride) {
    ushort4 v = reinterpret_cast<const ushort4*>(t1)[c];
    int f = (c * 4) & 127;
    ushort4 o;
    o.x = f2bf(gelu_f(bf2f(v.x) * scsh[f]   + scsh[128+f]));
    o.y = f2bf(gelu_f(bf2f(v.y) * scsh[f+1] + scsh[128+f+1]));
    o.z = f2bf(gelu_f(bf2f(v.z) * scsh[f+2] + scsh[128+f+2]));
    o.w = f2bf(gelu_f(bf2f(v.w) * scsh[f+3] + scsh[128+f+3]));
    reinterpret_cast<ushort4*>(h2)[c] = o;
  }
}

// ---------------- RGCN: out[n,o] = sum_{k,f} h[nbr[n,k],f] * W[o,k*128+f] --
// Block = 4 waves, 128 nodes. Wave = 32 nodes x 128 out-feats, all 16 slots.
// B (32KB/slot) double-buffered in LDS via global_load_lds: wave w stages
// frags w*8..w*8+7; all 4 waves consume all 32 frags (4x reuse). A gathered
// to VGPRs, 1-deep prefetch; issue pinned before MFMAs by sched_barrier(0);
// end-of-slot __syncthreads is the structural anti-sink fence.
template<bool STATS>
__global__ __launch_bounds__(256, 2) void rgcn_kernel(
    const unsigned short* __restrict__ h,
    const unsigned short* __restrict__ Wt,
    const int* __restrict__ graph,
    const float* __restrict__ bias,
    const float* __restrict__ xres,
    float* __restrict__ outf,
    unsigned short* __restrict__ outb,
    float* __restrict__ part)
{
  __shared__ unsigned short bsm[2][16384];    // 64KB B double buffer
  __shared__ float lds_s[4][128];
  __shared__ float lds_q[4][128];

  const int tid  = threadIdx.x;
  const int wv   = tid >> 6;
  const int lane = tid & 63;
  const int l15  = lane & 15;
  const int lq   = lane >> 4;
  const int nodebase = blockIdx.x * 128 + wv * 32;

  v4f acc[2][8];
#pragma unroll
  for (int rf = 0; rf < 2; ++rf)
#pragma unroll
    for (int c = 0; c < 8; ++c) acc[rf][c] = (v4f){0.f, 0.f, 0.f, 0.f};

  const int an0 = min(nodebase + l15, NN - 1);       // A-row node (rf=0)
  const int an1 = min(nodebase + 16 + l15, NN - 1);  // A-row node (rf=1)

  // preload all 16 neighbor indices per row, clamped, pre-scaled to elem offset
  int idx0[16], idx1[16];
  {
    const int4* g0 = reinterpret_cast<const int4*>(graph + an0 * 32);
    const int4* g1 = reinterpret_cast<const int4*>(graph + an1 * 32);
#pragma unroll
    for (int j = 0; j < 8; ++j) {
      int4 t0 = g0[j], t1v = g1[j];
      idx0[2*j]   = min(max(t0.y,  0), NN - 1) * 128;
      idx0[2*j+1] = min(max(t0.w,  0), NN - 1) * 128;
      idx1[2*j]   = min(max(t1v.y, 0), NN - 1) * 128;
      idx1[2*j+1] = min(max(t1v.w, 0), NN - 1) * 128;
    }
  }

  v8bf A0[2][4], A1[2][4];
  // A gather: 8 loads (16 rows x 64B segments per instr)
#define LOADA(buf_, s_) {                                             \
    const unsigned short* r0 = h + idx0[s_] + lq * 8;                 \
    const unsigned short* r1 = h + idx1[s_] + lq * 8;                 \
    _Pragma("unroll")                                                 \
    for (int w4 = 0; w4 < 4; ++w4) {                                  \
      A0[buf_][w4] = *reinterpret_cast<const v8bf*>(r0 + w4 * 32);    \
      A1[buf_][w4] = *reinterpret_cast<const v8bf*>(r1 + w4 * 32);    \
    }                                                                 \
  }

  // B stage: wave wv stages its 8 frags (8KB) of slot s_ into bsm[buf_].
  // HW adds lane*16 to the LDS dest; global src carries the matching lane*8.
#define STAGE(buf_, s_) {                                                     \
    const unsigned short* gsrc = Wt + (s_) * 16384 + wv * 4096 + lane * 8;    \
    unsigned short* ldst = &bsm[buf_][wv * 4096];                             \
    _Pragma("unroll")                                                         \
    for (int i = 0; i < 8; ++i) {                                             \
      __builtin_amdgcn_global_load_lds(                                       \
        (const __attribute__((address_space(1))) void*)(gsrc + i * 512),      \
        (__attribute__((address_space(3))) void*)(ldst + i * 512),            \
        16, 0, 0);                                                            \
    }                                                                         \
  }

  STAGE(0, 0)
  LOADA(0, 0)
  __syncthreads();                                   // stage(0) visible

#pragma unroll
  for (int s = 0; s < 16; ++s) {
    const int cur = s & 1, nxt = cur ^ 1;
    if (s < 15) {
      LOADA(nxt, s + 1)                              // A prefetch (regs)
      STAGE(nxt, s + 1)                              // B prefetch (LDS, async)
    }
    __builtin_amdgcn_sched_barrier(0);               // pin issue before MFMAs
#pragma unroll
    for (int w4 = 0; w4 < 4; ++w4) {
#pragma unroll
      for (int c = 0; c < 8; ++c) {
        v8bf b = *reinterpret_cast<const v8bf*>(&bsm[cur][(w4 * 8 + c) * 512 + lane * 8]);
        acc[0][c] = __builtin_amdgcn_mfma_f32_16x16x32_bf16(A0[cur][w4], b, acc[0][c], 0, 0, 0);
        acc[1][c] = __builtin_amdgcn_mfma_f32_16x16x32_bf16(A1[cur][w4], b, acc[1][c], 0, 0, 0);
      }
    }
    __syncthreads();                                 // drains vmcnt: stage+gather done
  }
#undef LOADA
#undef STAGE

  if constexpr (STATS) {
#pragma unroll
    for (int c = 0; c < 8; ++c) {
      float s = 0.f, q = 0.f;
#pragma unroll
      for (int rf = 0; rf < 2; ++rf) {
#pragma unroll
        for (int j = 0; j < 4; ++j) {
          int node = nodebase + rf * 16 + lq * 4 + j;   // C/D: row=(lane>>4)*4+reg
          float v  = acc[rf][c][j];
          if (node < NN) {
            s += v; q += v * v;
            outb[node * 128 + c * 16 + l15] = f2bf(v);  // col = lane&15
          }
        }
      }
      s += __shfl_xor(s, 16, 64); s += __shfl_xor(s, 32, 64);
      q += __shfl_xor(q, 16, 64); q += __shfl_xor(q, 32, 64);
      if (lq == 0) { lds_s[wv][c * 16 + l15] = s; lds_q[wv][c * 16 + l15] = q; }
    }
    __syncthreads();
    if (tid < 128) {
      float S = lds_s[0][tid] + lds_s[1][tid] + lds_s[2][tid] + lds_s[3][tid];
      float Q = lds_q[0][tid] + lds_q[1][tid] + lds_q[2][tid] + lds_q[3][tid];
      part[blockIdx.x * 256 + tid]       = S;
      part[blockIdx.x * 256 + 128 + tid] = Q;
    }
  } else {
#pragma unroll
    for (int c = 0; c < 8; ++c) {
      float bv = bias[c * 16 + l15];
#pragma unroll
      for (int rf = 0; rf < 2; ++rf) {
#pragma unroll
        for (int j = 0; j < 4; ++j) {
          int node = nodebase + rf * 16 + lq * 4 + j;
          if (node < NN) {
            int idx = node * 128 + c * 16 + l15;
            outf[idx] = acc[rf][c][j] + bv + xres[idx];
          }
        }
      }
    }
  }
}

extern "C" void kernel_launch(void* const* d_in, const int* in_sizes, int n_in,
                              void* d_out, int out_size, void* d_ws, size_t ws_size,
                              hipStream_t stream) {
  const float* x      = (const float*)d_in[0];
  const int*   graph  = (const int*)d_in[1];
  const float* gamma1 = (const float*)d_in[2];
  const float* beta1  = (const float*)d_in[3];
  const float* W1     = (const float*)d_in[4];
  // d_in[5] = b1 : provably cancels inside BN2 (per-feature shift), skipped
  const float* gamma2 = (const float*)d_in[6];
  const float* beta2  = (const float*)d_in[7];
  const float* W2     = (const float*)d_in[8];
  const float* b2     = (const float*)d_in[9];
  float* out = (float*)d_out;

  char* ws = (char*)d_ws;
  // ws layout (bytes): h1/h2 bf16 12.8M | t1 bf16 12.8M | Wt1 512K | Wt2 512K
  //                    | p1 256K | p2 400K | scsh1 1K | scsh2 1K   (~27.3MB total)
  unsigned short* h1  = (unsigned short*)(ws);
  unsigned short* t1  = (unsigned short*)(ws + 12800000);
  unsigned short* Wt1 = (unsigned short*)(ws + 25600000);
  unsigned short* Wt2 = (unsigned short*)(ws + 26124288);
  float* p1    = (float*)(ws + 26648576);
  float* p2    = (float*)(ws + 26910720);
  float* scsh1 = (float*)(ws + 27311104);
  float* scsh2 = (float*)(ws + 27312128);

  wconv_kernel<<<256, 256, 0, stream>>>(W1, W2, Wt1, Wt2);
  bn_stats_kernel<<<256, 256, 0, stream>>>(x, p1);
  bn_reduce_kernel<<<1, 1024, 0, stream>>>(p1, 256, gamma1, beta1, scsh1);
  apply1_kernel<<<2048, 256, 0, stream>>>(x, scsh1, h1);
  rgcn_kernel<true><<<391, 256, 0, stream>>>(h1, Wt1, graph, nullptr, nullptr, nullptr, t1, p2);
  bn_reduce_kernel<<<1, 1024, 0, stream>>>(p2, 391, gamma2, beta2, scsh2);
  apply2_kernel<<<2048, 256, 0, stream>>>(t1, scsh2, h1);   // h2 reuses h1 buffer
  rgcn_kernel<false><<<391, 256, 0, stream>>>(h1, Wt2, graph, b2, x, out, nullptr, nullptr);
}

// Round 7
// 205.400 us; speedup vs baseline: 1.9372x; 1.0114x over previous
//
#include <hip/hip_runtime.h>

// RGCNBlock: y = rgcn2(gelu(bn2(rgcn1(gelu(bn1(x)))))) + x
// N=50000 nodes, K=16 neighbors, F=128 features, f32 in/out.
// Matmuls in bf16 MFMA (16x16x32), stats/accum in f32. b1 cancels in BN2.
// rgcn R7: T3/T4 schedule — raw s_barrier (no drain) + counted
// s_waitcnt vmcnt(16): 16 VMEM ops issued/slot (8 A-gathers + 8 B-stages),
// so the counted wait drains only LAST slot's ops; this slot's prefetch
// stays in flight across the barrier. R6's __syncthreads drained vmcnt(0)
// per slot and exposed full gather latency (75us, MfmaUtil 13%).

#define NN 50000
#define FF 128

typedef __bf16 v8bf __attribute__((ext_vector_type(8)));
typedef float  v4f  __attribute__((ext_vector_type(4)));

__device__ __forceinline__ unsigned short f2bf(float f) {
  unsigned int u = __builtin_bit_cast(unsigned int, f);
  u += 0x7FFFu + ((u >> 16) & 1u);          // RNE
  return (unsigned short)(u >> 16);
}
__device__ __forceinline__ float bf2f(unsigned short s) {
  unsigned int u = ((unsigned int)s) << 16;
  return __builtin_bit_cast(float, u);
}
__device__ __forceinline__ float gelu_f(float y) {
  return 0.5f * y * (1.0f + erff(y * 0.70710678118654752f));
}

// ---------------- W (F x K*F f32) -> bf16 in MFMA-B-fragment order ----------
// frag id = k4*8 + c  (k4 = 32-wide K-window 0..63, c = 16-wide col tile 0..7)
// within frag: lane L holds W[c*16+(L&15), k4*32+(L>>4)*8 + j], j=0..7 (16B)
__global__ void wconv_kernel(const float* __restrict__ W1, const float* __restrict__ W2,
                             unsigned short* __restrict__ Wt1, unsigned short* __restrict__ Wt2) {
  int t = blockIdx.x * 256 + threadIdx.x;            // 65536 total
  const float* W = (t >= 32768) ? W2 : W1;
  unsigned short* Wt = (t >= 32768) ? Wt2 : Wt1;
  int r = t & 32767;
  int frag = r >> 6, lane = r & 63;
  int k4 = frag >> 3, c = frag & 7;
  int o  = c * 16 + (lane & 15);
  int kd = k4 * 32 + (lane >> 4) * 8;
  const float* src = W + o * 2048 + kd;
  unsigned short* dst = Wt + r * 8;
#pragma unroll
  for (int j = 0; j < 8; ++j) dst[j] = f2bf(src[j]);
}

// ---------------- BN stats over x (f32), deterministic two-phase ------------
__global__ void bn_stats_kernel(const float* __restrict__ x, float* __restrict__ part) {
  float s0=0,s1=0,s2=0,s3=0,q0=0,q1=0,q2=0,q3=0;
  for (int cb = blockIdx.x; cb < (NN*FF/1024); cb += 256) {
    float4 v = reinterpret_cast<const float4*>(x)[cb * 256 + threadIdx.x];
    s0+=v.x; q0+=v.x*v.x; s1+=v.y; q1+=v.y*v.y;
    s2+=v.z; q2+=v.z*v.z; s3+=v.w; q3+=v.w*v.w;
  }
  __shared__ float ls[1024], lsq[1024];
  int fb = (threadIdx.x & 31) * 4;
  int sl = threadIdx.x >> 5;
  ls[sl*128+fb]   = s0; ls[sl*128+fb+1]  = s1; ls[sl*128+fb+2]  = s2; ls[sl*128+fb+3]  = s3;
  lsq[sl*128+fb]  = q0; lsq[sl*128+fb+1] = q1; lsq[sl*128+fb+2] = q2; lsq[sl*128+fb+3] = q3;
  __syncthreads();
  if (threadIdx.x < 128) {
    float S=0,Q=0;
#pragma unroll
    for (int s2i=0; s2i<8; ++s2i){ S += ls[s2i*128+threadIdx.x]; Q += lsq[s2i*128+threadIdx.x]; }
    part[blockIdx.x*256 + threadIdx.x]       = S;
    part[blockIdx.x*256 + 128 + threadIdx.x] = Q;
  }
}

// ---------------- final reduce: 1 block x 1024 thr, 8 groups x 128 feats ----
__global__ __launch_bounds__(1024) void bn_reduce_kernel(
    const float* __restrict__ part, int nb,
    const float* __restrict__ gamma, const float* __restrict__ beta,
    float* __restrict__ scsh) {
  int f = threadIdx.x & 127;
  int g = threadIdx.x >> 7;                            // 0..7
  float S = 0.f, Q = 0.f;
  for (int b = g; b < nb; b += 8) {                    // independent loads, deep pipeline
    S += part[b * 256 + f];
    Q += part[b * 256 + 128 + f];
  }
  __shared__ float ls[8][128], lq[8][128];
  ls[g][f] = S; lq[g][f] = Q;
  __syncthreads();
  if (threadIdx.x < 128) {
    float St = 0.f, Qt = 0.f;
#pragma unroll
    for (int i = 0; i < 8; ++i) { St += ls[i][f]; Qt += lq[i][f]; }
    float inv  = 1.0f / (float)NN;
    float mean = St * inv;
    float var  = fmaxf(Qt * inv - mean * mean, 0.0f);
    float sc   = gamma[f] * rsqrtf(var + 1e-5f);
    scsh[f]       = sc;
    scsh[128 + f] = beta[f] - mean * sc;
  }
}

// ---------------- apply BN + GELU, f32 source -> bf16 ----------------------
__global__ void apply1_kernel(const float* __restrict__ x, const float* __restrict__ scsh,
                              unsigned short* __restrict__ h1) {
  int stride = gridDim.x * blockDim.x;
  for (int c = blockIdx.x * blockDim.x + threadIdx.x; c < NN*FF/4; c += stride) {
    float4 v = reinterpret_cast<const float4*>(x)[c];
    int f = (c * 4) & 127;
    ushort4 o;
    o.x = f2bf(gelu_f(v.x * scsh[f]   + scsh[128+f]));
    o.y = f2bf(gelu_f(v.y * scsh[f+1] + scsh[128+f+1]));
    o.z = f2bf(gelu_f(v.z * scsh[f+2] + scsh[128+f+2]));
    o.w = f2bf(gelu_f(v.w * scsh[f+3] + scsh[128+f+3]));
    reinterpret_cast<ushort4*>(h1)[c] = o;
  }
}

// ---------------- apply BN + GELU, bf16 source -> bf16 ---------------------
__global__ void apply2_kernel(const unsigned short* __restrict__ t1, const float* __restrict__ scsh,
                              unsigned short* __restrict__ h2) {
  int stride = gridDim.x * blockDim.x;
  for (int c = blockIdx.x * blockDim.x + threadIdx.x; c < NN*FF/4; c += stride) {
    ushort4 v = reinterpret_cast<const ushort4*>(t1)[c];
    int f = (c * 4) & 127;
    ushort4 o;
    o.x = f2bf(gelu_f(bf2f(v.x) * scsh[f]   + scsh[128+f]));
    o.y = f2bf(gelu_f(bf2f(v.y) * scsh[f+1] + scsh[128+f+1]));
    o.z = f2bf(gelu_f(bf2f(v.z) * scsh[f+2] + scsh[128+f+2]));
    o.w = f2bf(gelu_f(bf2f(v.w) * scsh[f+3] + scsh[128+f+3]));
    reinterpret_cast<ushort4*>(h2)[c] = o;
  }
}

// ---------------- RGCN: out[n,o] = sum_{k,f} h[nbr[n,k],f] * W[o,k*128+f] --
// Block = 4 waves, 128 nodes. Wave = 32 nodes x 128 out-feats, all 16 slots.
// Per slot: issue {8 A-gathers + 8 B-stages} for slot s+1 (16 VMEM ops),
// s_waitcnt vmcnt(16) (waits ONLY last slot's 16), raw s_barrier, MFMA on
// slot s, raw s_barrier (LDS WAR fence). Never vmcnt(0) in the loop.
template<bool STATS>
__global__ __launch_bounds__(256, 2) void rgcn_kernel(
    const unsigned short* __restrict__ h,
    const unsigned short* __restrict__ Wt,
    const int* __restrict__ graph,
    const float* __restrict__ bias,
    const float* __restrict__ xres,
    float* __restrict__ outf,
    unsigned short* __restrict__ outb,
    float* __restrict__ part)
{
  __shared__ unsigned short bsm[2][16384];    // 64KB B double buffer

  const int tid  = threadIdx.x;
  const int wv   = tid >> 6;
  const int lane = tid & 63;
  const int l15  = lane & 15;
  const int lq   = lane >> 4;
  const int nodebase = blockIdx.x * 128 + wv * 32;

  v4f acc[2][8];
#pragma unroll
  for (int rf = 0; rf < 2; ++rf)
#pragma unroll
    for (int c = 0; c < 8; ++c) acc[rf][c] = (v4f){0.f, 0.f, 0.f, 0.f};

  const int an0 = min(nodebase + l15, NN - 1);       // A-row node (rf=0)
  const int an1 = min(nodebase + 16 + l15, NN - 1);  // A-row node (rf=1)

  // preload all 16 neighbor indices per row, clamped, pre-scaled to elem offset
  int idx0[16], idx1[16];
  {
    const int4* g0 = reinterpret_cast<const int4*>(graph + an0 * 32);
    const int4* g1 = reinterpret_cast<const int4*>(graph + an1 * 32);
#pragma unroll
    for (int j = 0; j < 8; ++j) {
      int4 t0 = g0[j], t1v = g1[j];
      idx0[2*j]   = min(max(t0.y,  0), NN - 1) * 128;
      idx0[2*j+1] = min(max(t0.w,  0), NN - 1) * 128;
      idx1[2*j]   = min(max(t1v.y, 0), NN - 1) * 128;
      idx1[2*j+1] = min(max(t1v.w, 0), NN - 1) * 128;
    }
  }

  v8bf A0[2][4], A1[2][4];
  // A gather: 8x global_load_dwordx4 (2 rows x 4 segments of 16B)
#define LOADA(buf_, s_) {                                             \
    const unsigned short* r0 = h + idx0[s_] + lq * 8;                 \
    const unsigned short* r1 = h + idx1[s_] + lq * 8;                 \
    _Pragma("unroll")                                                 \
    for (int w4 = 0; w4 < 4; ++w4) {                                  \
      A0[buf_][w4] = *reinterpret_cast<const v8bf*>(r0 + w4 * 32);    \
      A1[buf_][w4] = *reinterpret_cast<const v8bf*>(r1 + w4 * 32);    \
    }                                                                 \
  }

  // B stage: wave wv stages its 8 frags (8KB) of slot s_ into bsm[buf_].
  // 8x global_load_lds_dwordx4 (HW adds lane*16 to the LDS base).
#define STAGE(buf_, s_) {                                                     \
    const unsigned short* gsrc = Wt + (s_) * 16384 + wv * 4096 + lane * 8;    \
    unsigned short* ldst = &bsm[buf_][wv * 4096];                             \
    _Pragma("unroll")                                                         \
    for (int i = 0; i < 8; ++i) {                                             \
      __builtin_amdgcn_global_load_lds(                                       \
        (const __attribute__((address_space(1))) void*)(gsrc + i * 512),      \
        (__attribute__((address_space(3))) void*)(ldst + i * 512),            \
        16, 0, 0);                                                            \
    }                                                                         \
  }

  // Slot body. Issue next-slot loads FIRST (16 vm ops), pin with
  // sched_barrier, counted vmcnt, raw barriers around the MFMA cluster.
#define SLOT(s_) {                                                            \
    if ((s_) < 15) {                                                          \
      LOADA(((s_) + 1) & 1, (s_) + 1)                                         \
      STAGE(((s_) + 1) & 1, (s_) + 1)                                         \
    }                                                                         \
    __builtin_amdgcn_sched_barrier(0);                                        \
    if ((s_) < 15) { asm volatile("s_waitcnt vmcnt(16)" ::: "memory"); }      \
    else           { asm volatile("s_waitcnt vmcnt(0)"  ::: "memory"); }      \
    __builtin_amdgcn_sched_barrier(0);                                        \
    __builtin_amdgcn_s_barrier();      /* all waves' stage(cur) visible */    \
    __builtin_amdgcn_sched_barrier(0);                                        \
    {                                                                         \
      const int cur_ = (s_) & 1;                                              \
      _Pragma("unroll")                                                       \
      for (int w4 = 0; w4 < 4; ++w4) {                                        \
        _Pragma("unroll")                                                     \
        for (int c = 0; c < 8; ++c) {                                         \
          v8bf b = *reinterpret_cast<const v8bf*>(                            \
              &bsm[cur_][(w4 * 8 + c) * 512 + lane * 8]);                     \
          acc[0][c] = __builtin_amdgcn_mfma_f32_16x16x32_bf16(                \
                        A0[cur_][w4], b, acc[0][c], 0, 0, 0);                 \
          acc[1][c] = __builtin_amdgcn_mfma_f32_16x16x32_bf16(                \
                        A1[cur_][w4], b, acc[1][c], 0, 0, 0);                 \
        }                                                                     \
      }                                                                       \
    }                                                                         \
    __builtin_amdgcn_sched_barrier(0);                                        \
    __builtin_amdgcn_s_barrier();      /* WAR fence: bsm[cur] safe to reuse */\
    __builtin_amdgcn_sched_barrier(0);                                        \
  }

  STAGE(0, 0)
  LOADA(0, 0)

  SLOT(0)  SLOT(1)  SLOT(2)  SLOT(3)
  SLOT(4)  SLOT(5)  SLOT(6)  SLOT(7)
  SLOT(8)  SLOT(9)  SLOT(10) SLOT(11)
  SLOT(12) SLOT(13) SLOT(14) SLOT(15)
#undef SLOT
#undef LOADA
#undef STAGE

  if constexpr (STATS) {
    __shared__ float lds_s[4][128];
    __shared__ float lds_q[4][128];
#pragma unroll
    for (int c = 0; c < 8; ++c) {
      float s = 0.f, q = 0.f;
#pragma unroll
      for (int rf = 0; rf < 2; ++rf) {
#pragma unroll
        for (int j = 0; j < 4; ++j) {
          int node = nodebase + rf * 16 + lq * 4 + j;   // C/D: row=(lane>>4)*4+reg
          float v  = acc[rf][c][j];
          if (node < NN) {
            s += v; q += v * v;
            outb[node * 128 + c * 16 + l15] = f2bf(v);  // col = lane&15
          }
        }
      }
      s += __shfl_xor(s, 16, 64); s += __shfl_xor(s, 32, 64);
      q += __shfl_xor(q, 16, 64); q += __shfl_xor(q, 32, 64);
      if (lq == 0) { lds_s[wv][c * 16 + l15] = s; lds_q[wv][c * 16 + l15] = q; }
    }
    __syncthreads();
    if (tid < 128) {
      float S = lds_s[0][tid] + lds_s[1][tid] + lds_s[2][tid] + lds_s[3][tid];
      float Q = lds_q[0][tid] + lds_q[1][tid] + lds_q[2][tid] + lds_q[3][tid];
      part[blockIdx.x * 256 + tid]       = S;
      part[blockIdx.x * 256 + 128 + tid] = Q;
    }
  } else {
#pragma unroll
    for (int c = 0; c < 8; ++c) {
      float bv = bias[c * 16 + l15];
#pragma unroll
      for (int rf = 0; rf < 2; ++rf) {
#pragma unroll
        for (int j = 0; j < 4; ++j) {
          int node = nodebase + rf * 16 + lq * 4 + j;
          if (node < NN) {
            int idx = node * 128 + c * 16 + l15;
            outf[idx] = acc[rf][c][j] + bv + xres[idx];
          }
        }
      }
    }
  }
}

extern "C" void kernel_launch(void* const* d_in, const int* in_sizes, int n_in,
                              void* d_out, int out_size, void* d_ws, size_t ws_size,
                              hipStream_t stream) {
  const float* x      = (const float*)d_in[0];
  const int*   graph  = (const int*)d_in[1];
  const float* gamma1 = (const float*)d_in[2];
  const float* beta1  = (const float*)d_in[3];
  const float* W1     = (const float*)d_in[4];
  // d_in[5] = b1 : provably cancels inside BN2 (per-feature shift), skipped
  const float* gamma2 = (const float*)d_in[6];
  const float* beta2  = (const float*)d_in[7];
  const float* W2     = (const float*)d_in[8];
  const float* b2     = (const float*)d_in[9];
  float* out = (float*)d_out;

  char* ws = (char*)d_ws;
  // ws layout (bytes): h1/h2 bf16 12.8M | t1 bf16 12.8M | Wt1 512K | Wt2 512K
  //                    | p1 256K | p2 400K | scsh1 1K | scsh2 1K   (~27.3MB total)
  unsigned short* h1  = (unsigned short*)(ws);
  unsigned short* t1  = (unsigned short*)(ws + 12800000);
  unsigned short* Wt1 = (unsigned short*)(ws + 25600000);
  unsigned short* Wt2 = (unsigned short*)(ws + 26124288);
  float* p1    = (float*)(ws + 26648576);
  float* p2    = (float*)(ws + 26910720);
  float* scsh1 = (float*)(ws + 27311104);
  float* scsh2 = (float*)(ws + 27312128);

  wconv_kernel<<<256, 256, 0, stream>>>(W1, W2, Wt1, Wt2);
  bn_stats_kernel<<<256, 256, 0, stream>>>(x, p1);
  bn_reduce_kernel<<<1, 1024, 0, stream>>>(p1, 256, gamma1, beta1, scsh1);
  apply1_kernel<<<2048, 256, 0, stream>>>(x, scsh1, h1);
  rgcn_kernel<true><<<391, 256, 0, stream>>>(h1, Wt1, graph, nullptr, nullptr, nullptr, t1, p2);
  bn_reduce_kernel<<<1, 1024, 0, stream>>>(p2, 391, gamma2, beta2, scsh2);
  apply2_kernel<<<2048, 256, 0, stream>>>(t1, scsh2, h1);   // h2 reuses h1 buffer
  rgcn_kernel<false><<<391, 256, 0, stream>>>(h1, Wt2, graph, b2, x, out, nullptr, nullptr);
}

// Round 8
// 201.155 us; speedup vs baseline: 1.9781x; 1.0211x over previous
//
#include <hip/hip_runtime.h>

// RGCNBlock: y = rgcn2(gelu(bn2(rgcn1(gelu(bn1(x)))))) + x
// N=50000, K=16, F=128, f32 in/out. bf16 MFMA 16x16x32; b1 cancels in BN2.
// R8: regime = random-gather L2-miss traffic at ~1.6 TB/s (dur==bytes/1.6TB/s
// across R2/R6/R7; FETCH ~= 8 XCD x 12.8MB compulsory). Levers: (1) perfect
// balance: 500 blocks x 100 nodes (76%->98% makespan eff); (2) single 32KB
// B-LDS -> 4 blocks/CU capacity; (3) apply2 folded into rgcn2's gather
// (sigmoid-gelu in-register, saves 25.6MB streaming + launch); (4) setprio.

#define NN  50000
#define NB  500
#define NPB 100

typedef __bf16 v8bf __attribute__((ext_vector_type(8)));
typedef unsigned short u8s __attribute__((ext_vector_type(8)));
typedef float  v4f  __attribute__((ext_vector_type(4)));

__device__ __forceinline__ unsigned short f2bf(float f) {
  unsigned int u = __builtin_bit_cast(unsigned int, f);
  u += 0x7FFFu + ((u >> 16) & 1u);          // RNE
  return (unsigned short)(u >> 16);
}
__device__ __forceinline__ float bf2f(unsigned short s) {
  unsigned int u = ((unsigned int)s) << 16;
  return __builtin_bit_cast(float, u);
}
__device__ __forceinline__ float gelu_f(float y) {
  return 0.5f * y * (1.0f + erff(y * 0.70710678118654752f));
}

// ---------------- W (F x K*F f32) -> bf16 in MFMA-B-fragment order ----------
__global__ void wconv_kernel(const float* __restrict__ W1, const float* __restrict__ W2,
                             unsigned short* __restrict__ Wt1, unsigned short* __restrict__ Wt2) {
  int t = blockIdx.x * 256 + threadIdx.x;            // 65536 total
  const float* W = (t >= 32768) ? W2 : W1;
  unsigned short* Wt = (t >= 32768) ? Wt2 : Wt1;
  int r = t & 32767;
  int frag = r >> 6, lane = r & 63;
  int k4 = frag >> 3, c = frag & 7;
  int o  = c * 16 + (lane & 15);
  int kd = k4 * 32 + (lane >> 4) * 8;
  const float* src = W + o * 2048 + kd;
  unsigned short* dst = Wt + r * 8;
#pragma unroll
  for (int j = 0; j < 8; ++j) dst[j] = f2bf(src[j]);
}

// ---------------- BN stats over x (f32), deterministic two-phase ------------
__global__ void bn_stats_kernel(const float* __restrict__ x, float* __restrict__ part) {
  float s0=0,s1=0,s2=0,s3=0,q0=0,q1=0,q2=0,q3=0;
  for (int cb = blockIdx.x; cb < (NN*128/1024); cb += 256) {
    float4 v = reinterpret_cast<const float4*>(x)[cb * 256 + threadIdx.x];
    s0+=v.x; q0+=v.x*v.x; s1+=v.y; q1+=v.y*v.y;
    s2+=v.z; q2+=v.z*v.z; s3+=v.w; q3+=v.w*v.w;
  }
  __shared__ float ls[1024], lsq[1024];
  int fb = (threadIdx.x & 31) * 4;
  int sl = threadIdx.x >> 5;
  ls[sl*128+fb]   = s0; ls[sl*128+fb+1]  = s1; ls[sl*128+fb+2]  = s2; ls[sl*128+fb+3]  = s3;
  lsq[sl*128+fb]  = q0; lsq[sl*128+fb+1] = q1; lsq[sl*128+fb+2] = q2; lsq[sl*128+fb+3] = q3;
  __syncthreads();
  if (threadIdx.x < 128) {
    float S=0,Q=0;
#pragma unroll
    for (int s2i=0; s2i<8; ++s2i){ S += ls[s2i*128+threadIdx.x]; Q += lsq[s2i*128+threadIdx.x]; }
    part[blockIdx.x*256 + threadIdx.x]       = S;
    part[blockIdx.x*256 + 128 + threadIdx.x] = Q;
  }
}

// ---------------- final reduce: 1 block x 1024 thr, 8 groups x 128 feats ----
__global__ __launch_bounds__(1024) void bn_reduce_kernel(
    const float* __restrict__ part, int nb,
    const float* __restrict__ gamma, const float* __restrict__ beta,
    float* __restrict__ scsh) {
  int f = threadIdx.x & 127;
  int g = threadIdx.x >> 7;
  float S = 0.f, Q = 0.f;
  for (int b = g; b < nb; b += 8) {
    S += part[b * 256 + f];
    Q += part[b * 256 + 128 + f];
  }
  __shared__ float ls[8][128], lq[8][128];
  ls[g][f] = S; lq[g][f] = Q;
  __syncthreads();
  if (threadIdx.x < 128) {
    float St = 0.f, Qt = 0.f;
#pragma unroll
    for (int i = 0; i < 8; ++i) { St += ls[i][f]; Qt += lq[i][f]; }
    float inv  = 1.0f / (float)NN;
    float mean = St * inv;
    float var  = fmaxf(Qt * inv - mean * mean, 0.0f);
    float sc   = gamma[f] * rsqrtf(var + 1e-5f);
    scsh[f]       = sc;
    scsh[128 + f] = beta[f] - mean * sc;
  }
}

// ---------------- apply BN + GELU (exact erf), f32 source -> bf16 -----------
__global__ void apply1_kernel(const float* __restrict__ x, const float* __restrict__ scsh,
                              unsigned short* __restrict__ h1) {
  int stride = gridDim.x * blockDim.x;
  for (int c = blockIdx.x * blockDim.x + threadIdx.x; c < NN*128/4; c += stride) {
    float4 v = reinterpret_cast<const float4*>(x)[c];
    int f = (c * 4) & 127;
    ushort4 o;
    o.x = f2bf(gelu_f(v.x * scsh[f]   + scsh[128+f]));
    o.y = f2bf(gelu_f(v.y * scsh[f+1] + scsh[128+f+1]));
    o.z = f2bf(gelu_f(v.z * scsh[f+2] + scsh[128+f+2]));
    o.w = f2bf(gelu_f(v.w * scsh[f+3] + scsh[128+f+3]));
    reinterpret_cast<ushort4*>(h1)[c] = o;
  }
}

// ---------------- RGCN ------------------------------------------------------
// Block = 4 waves, EXACTLY 100 nodes (500 blocks => ~2/CU, ~98% balance).
// Pad rows (node >= nb0+100) clamp their gather to an in-range row (L2-hot
// dup, no extra miss bytes); stores/stats guarded. B: single 32KB LDS tile,
// staged by all 4 waves (wave wv: frags wv*8..wv*8+7) via global_load_lds.
// MODE 0 (rgcn1): A = h1 bf16 direct; epilogue = t1 store + BN2 partial sums.
// MODE 1 (rgcn2): A = raw t1 rows, BN+GELU applied in-register (sigmoid-gelu,
// scsh2 pairs broadcast from LDS); epilogue = +b2 +x residual store.
template<int MODE>
__global__ __launch_bounds__(256, 2) void rgcn_kernel(
    const unsigned short* __restrict__ hb,
    const unsigned short* __restrict__ Wt,
    const int* __restrict__ graph,
    const float* __restrict__ scsh,
    const float* __restrict__ bias,
    const float* __restrict__ xres,
    float* __restrict__ outf,
    unsigned short* __restrict__ outb,
    float* __restrict__ part)
{
  __shared__ unsigned short bsm[16384];      // 32KB single B buffer
  __shared__ float2 scp[128];                // (sc, sh) pairs for MODE 1

  const int tid  = threadIdx.x;
  const int wv   = tid >> 6;
  const int lane = tid & 63;
  const int l15  = lane & 15;
  const int lq   = lane >> 4;
  const int nb0  = blockIdx.x * NPB;
  const int nend = nb0 + NPB;                // 500*100 = 50000 exactly

  if (MODE == 1 && tid < 128) scp[tid] = make_float2(scsh[tid], scsh[128 + tid]);

  v4f acc[2][8];
#pragma unroll
  for (int rf = 0; rf < 2; ++rf)
#pragma unroll
    for (int c = 0; c < 8; ++c) acc[rf][c] = (v4f){0.f, 0.f, 0.f, 0.f};

  const int an0 = min(nb0 + wv * 32 + l15,      nend - 1);   // pad rows -> dup
  const int an1 = min(nb0 + wv * 32 + 16 + l15, nend - 1);

  int idx0[16], idx1[16];
  {
    const int4* g0 = reinterpret_cast<const int4*>(graph + an0 * 32);
    const int4* g1 = reinterpret_cast<const int4*>(graph + an1 * 32);
#pragma unroll
    for (int j = 0; j < 8; ++j) {
      int4 t0 = g0[j], t1v = g1[j];
      idx0[2*j]   = min(max(t0.y,  0), NN - 1) * 128;
      idx0[2*j+1] = min(max(t0.w,  0), NN - 1) * 128;
      idx1[2*j]   = min(max(t1v.y, 0), NN - 1) * 128;
      idx1[2*j+1] = min(max(t1v.w, 0), NN - 1) * 128;
    }
  }

  u8s R0[2][4], R1[2][4];                    // raw gathered rows, double-buffered
#define LOADA(buf_, s_) {                                             \
    const unsigned short* r0 = hb + idx0[s_] + lq * 8;                \
    const unsigned short* r1 = hb + idx1[s_] + lq * 8;                \
    _Pragma("unroll")                                                 \
    for (int w4 = 0; w4 < 4; ++w4) {                                  \
      R0[buf_][w4] = *reinterpret_cast<const u8s*>(r0 + w4 * 32);     \
      R1[buf_][w4] = *reinterpret_cast<const u8s*>(r1 + w4 * 32);     \
    }                                                                 \
  }

#define STAGE(s_) {                                                           \
    const unsigned short* gsrc = Wt + (s_) * 16384 + wv * 4096 + lane * 8;    \
    unsigned short* ldst = &bsm[wv * 4096];                                   \
    _Pragma("unroll")                                                         \
    for (int i = 0; i < 8; ++i) {                                             \
      __builtin_amdgcn_global_load_lds(                                       \
        (const __attribute__((address_space(1))) void*)(gsrc + i * 512),      \
        (__attribute__((address_space(3))) void*)(ldst + i * 512),            \
        16, 0, 0);                                                            \
    }                                                                         \
  }

#define SLOT(s_) {                                                            \
    if ((s_) < 15) LOADA(((s_) + 1) & 1, (s_) + 1)                            \
    __builtin_amdgcn_sched_barrier(0);                                        \
    __builtin_amdgcn_s_setprio(1);                                            \
    {                                                                         \
      const int cur_ = (s_) & 1;                                              \
      _Pragma("unroll")                                                       \
      for (int w4 = 0; w4 < 4; ++w4) {                                        \
        v8bf a0v, a1v;                                                        \
        if constexpr (MODE == 0) {                                            \
          a0v = __builtin_bit_cast(v8bf, R0[cur_][w4]);                       \
          a1v = __builtin_bit_cast(v8bf, R1[cur_][w4]);                       \
        } else {                                                              \
          _Pragma("unroll")                                                   \
          for (int j = 0; j < 8; ++j) {                                       \
            float2 ss = scp[w4 * 32 + lq * 8 + j];                            \
            float t0 = bf2f(R0[cur_][w4][j]) * ss.x + ss.y;                   \
            float t1 = bf2f(R1[cur_][w4][j]) * ss.x + ss.y;                   \
            a0v[j] = (__bf16)(t0 * __builtin_amdgcn_rcpf(                     \
                         1.0f + __expf(-1.702f * t0)));                       \
            a1v[j] = (__bf16)(t1 * __builtin_amdgcn_rcpf(                     \
                         1.0f + __expf(-1.702f * t1)));                       \
          }                                                                   \
        }                                                                     \
        _Pragma("unroll")                                                     \
        for (int c = 0; c < 8; ++c) {                                         \
          v8bf b = *reinterpret_cast<const v8bf*>(                            \
              &bsm[(w4 * 8 + c) * 512 + lane * 8]);                           \
          acc[0][c] = __builtin_amdgcn_mfma_f32_16x16x32_bf16(                \
                        a0v, b, acc[0][c], 0, 0, 0);                          \
          acc[1][c] = __builtin_amdgcn_mfma_f32_16x16x32_bf16(                \
                        a1v, b, acc[1][c], 0, 0, 0);                          \
        }                                                                     \
      }                                                                       \
    }                                                                         \
    __builtin_amdgcn_s_setprio(0);                                            \
    __builtin_amdgcn_sched_barrier(0);                                        \
    __builtin_amdgcn_s_barrier();   /* all waves done reading bsm */          \
    __builtin_amdgcn_sched_barrier(0);                                        \
    if ((s_) < 15) STAGE((s_) + 1)                                            \
    __syncthreads();                /* stage visible; gathers drained */      \
  }

  STAGE(0)
  LOADA(0, 0)
  __syncthreads();

  SLOT(0)  SLOT(1)  SLOT(2)  SLOT(3)
  SLOT(4)  SLOT(5)  SLOT(6)  SLOT(7)
  SLOT(8)  SLOT(9)  SLOT(10) SLOT(11)
  SLOT(12) SLOT(13) SLOT(14) SLOT(15)
#undef SLOT
#undef LOADA
#undef STAGE

  if constexpr (MODE == 0) {
    // stats + t1 store; LDS scratch reuses bsm (dead after k-loop)
    float* lds_s = reinterpret_cast<float*>(bsm);          // [4][128]
    float* lds_q = lds_s + 512;
#pragma unroll
    for (int c = 0; c < 8; ++c) {
      float s = 0.f, q = 0.f;
#pragma unroll
      for (int rf = 0; rf < 2; ++rf) {
#pragma unroll
        for (int j = 0; j < 4; ++j) {
          int node = nb0 + wv * 32 + rf * 16 + lq * 4 + j;  // row=(lane>>4)*4+reg
          float v  = acc[rf][c][j];
          if (node < nend) {
            s += v; q += v * v;
            outb[node * 128 + c * 16 + l15] = f2bf(v);      // col = lane&15
          }
        }
      }
      s += __shfl_xor(s, 16, 64); s += __shfl_xor(s, 32, 64);
      q += __shfl_xor(q, 16, 64); q += __shfl_xor(q, 32, 64);
      if (lq == 0) { lds_s[wv * 128 + c * 16 + l15] = s; lds_q[wv * 128 + c * 16 + l15] = q; }
    }
    __syncthreads();
    if (tid < 128) {
      float S = lds_s[tid] + lds_s[128 + tid] + lds_s[256 + tid] + lds_s[384 + tid];
      float Q = lds_q[tid] + lds_q[128 + tid] + lds_q[256 + tid] + lds_q[384 + tid];
      part[blockIdx.x * 256 + tid]       = S;
      part[blockIdx.x * 256 + 128 + tid] = Q;
    }
  } else {
#pragma unroll
    for (int c = 0; c < 8; ++c) {
      float bv = bias[c * 16 + l15];
#pragma unroll
      for (int rf = 0; rf < 2; ++rf) {
#pragma unroll
        for (int j = 0; j < 4; ++j) {
          int node = nb0 + wv * 32 + rf * 16 + lq * 4 + j;
          if (node < nend) {
            int idx = node * 128 + c * 16 + l15;
            outf[idx] = acc[rf][c][j] + bv + xres[idx];
          }
        }
      }
    }
  }
}

extern "C" void kernel_launch(void* const* d_in, const int* in_sizes, int n_in,
                              void* d_out, int out_size, void* d_ws, size_t ws_size,
                              hipStream_t stream) {
  const float* x      = (const float*)d_in[0];
  const int*   graph  = (const int*)d_in[1];
  const float* gamma1 = (const float*)d_in[2];
  const float* beta1  = (const float*)d_in[3];
  const float* W1     = (const float*)d_in[4];
  // d_in[5] = b1 : cancels inside BN2 (per-feature shift), skipped
  const float* gamma2 = (const float*)d_in[6];
  const float* beta2  = (const float*)d_in[7];
  const float* W2     = (const float*)d_in[8];
  const float* b2     = (const float*)d_in[9];
  float* out = (float*)d_out;

  char* ws = (char*)d_ws;
  // ws: h1 12.8M | t1 12.8M | Wt1 512K | Wt2 512K | p1 256K | p2 512K | scsh x2
  unsigned short* h1  = (unsigned short*)(ws);
  unsigned short* t1  = (unsigned short*)(ws + 12800000);
  unsigned short* Wt1 = (unsigned short*)(ws + 25600000);
  unsigned short* Wt2 = (unsigned short*)(ws + 26124288);
  float* p1    = (float*)(ws + 26648576);
  float* p2    = (float*)(ws + 26910720);
  float* scsh1 = (float*)(ws + 27422720);
  float* scsh2 = (float*)(ws + 27423744);

  wconv_kernel<<<256, 256, 0, stream>>>(W1, W2, Wt1, Wt2);
  bn_stats_kernel<<<256, 256, 0, stream>>>(x, p1);
  bn_reduce_kernel<<<1, 1024, 0, stream>>>(p1, 256, gamma1, beta1, scsh1);
  apply1_kernel<<<2048, 256, 0, stream>>>(x, scsh1, h1);
  rgcn_kernel<0><<<NB, 256, 0, stream>>>(h1, Wt1, graph, nullptr, nullptr, nullptr,
                                         nullptr, t1, p2);
  bn_reduce_kernel<<<1, 1024, 0, stream>>>(p2, NB, gamma2, beta2, scsh2);
  rgcn_kernel<1><<<NB, 256, 0, stream>>>(t1, Wt2, graph, scsh2, b2, x,
                                         out, nullptr, nullptr);
}